// Round 9
// baseline (177.087 us; speedup 1.0000x reference)
//
#include <hip/hip_runtime.h>
#include <hip/hip_fp16.h>

#define LN_EPS 1e-5f

static __device__ __forceinline__ float4 f4zero() { return make_float4(0.f, 0.f, 0.f, 0.f); }

// ---------------------------------------------------------------------------
// K1: feat[N][32](fp16) = X[N][128] @ Wf[128][32] + bf ; skill[N] = (int)X[n][0]
// 4 rows/thread (r0 + i*ceil(N/4): four coalesced streams). LDS cost scales
// as 4/R bytes per FMA: R=1 was 31 us of ds_read_b128 issue (the hidden
// bottleneck R2-R6), R=4 -> 7.8 us < HBM floor (9.2 us) => memory-bound.
// VALU floor 5.2 us. launch_bounds(256,4): VGPR cap 128, live ~85 fits
// (R7 lesson: never raise per-thread work under a 64-reg cap).
// ---------------------------------------------------------------------------
__global__ __launch_bounds__(256, 4) void k_feat(
    const float* __restrict__ X, const float* __restrict__ Wf,
    const float* __restrict__ bf, __half* __restrict__ feat,
    int* __restrict__ skill, int N)
{
    __shared__ float Wl[128 * 32];
    for (int i = threadIdx.x; i < 128 * 32; i += 256) Wl[i] = Wf[i];
    __syncthreads();

    const int gid = blockIdx.x * 256 + threadIdx.x;
    const int r0  = gid >> 3;          // thread handles rows r0 + i*q, i=0..3
    const int dg  = gid & 7;           // dims 4*dg .. 4*dg+3
    const int q   = (N + 3) >> 2;
    if (r0 >= q) return;

    int  rr[4];
    bool vv[4];
    const float4* __restrict__ Xp[4];
    #pragma unroll
    for (int i = 0; i < 4; ++i) {
        rr[i] = r0 + i * q;
        vv[i] = (rr[i] < N);
        Xp[i] = (const float4*)X + (size_t)(vv[i] ? rr[i] : 0) * 32;
    }

    const float4* __restrict__ W4 = (const float4*)Wl;
    const float4 bias = *(const float4*)(bf + 4 * dg);
    float4 acc[4] = {bias, bias, bias, bias};

    for (int f4 = 0; f4 < 32; ++f4) {
        float4 xv[4];
        #pragma unroll
        for (int i = 0; i < 4; ++i) xv[i] = vv[i] ? Xp[i][f4] : f4zero();

        if (f4 == 0 && dg == 0) {
            #pragma unroll
            for (int i = 0; i < 4; ++i)
                if (vv[i]) skill[rr[i]] = (int)xv[i].x;   // trunc == astype(int32)
        }

        const float4 w0 = W4[(4 * f4 + 0) * 8 + dg];
        const float4 w1 = W4[(4 * f4 + 1) * 8 + dg];
        const float4 w2 = W4[(4 * f4 + 2) * 8 + dg];
        const float4 w3 = W4[(4 * f4 + 3) * 8 + dg];

        #pragma unroll
        for (int i = 0; i < 4; ++i) {
            acc[i].x = fmaf(xv[i].x, w0.x, acc[i].x);
            acc[i].y = fmaf(xv[i].x, w0.y, acc[i].y);
            acc[i].z = fmaf(xv[i].x, w0.z, acc[i].z);
            acc[i].w = fmaf(xv[i].x, w0.w, acc[i].w);
            acc[i].x = fmaf(xv[i].y, w1.x, acc[i].x);
            acc[i].y = fmaf(xv[i].y, w1.y, acc[i].y);
            acc[i].z = fmaf(xv[i].y, w1.z, acc[i].z);
            acc[i].w = fmaf(xv[i].y, w1.w, acc[i].w);
            acc[i].x = fmaf(xv[i].z, w2.x, acc[i].x);
            acc[i].y = fmaf(xv[i].z, w2.y, acc[i].y);
            acc[i].z = fmaf(xv[i].z, w2.z, acc[i].z);
            acc[i].w = fmaf(xv[i].z, w2.w, acc[i].w);
            acc[i].x = fmaf(xv[i].w, w3.x, acc[i].x);
            acc[i].y = fmaf(xv[i].w, w3.y, acc[i].y);
            acc[i].z = fmaf(xv[i].w, w3.z, acc[i].z);
            acc[i].w = fmaf(xv[i].w, w3.w, acc[i].w);
        }
    }

    #pragma unroll
    for (int i = 0; i < 4; ++i) {
        if (vv[i]) {
            union { __half2 h2[2]; uint2 u; } cv;
            cv.h2[0] = __float22half2_rn(make_float2(acc[i].x, acc[i].y));
            cv.h2[1] = __float22half2_rn(make_float2(acc[i].z, acc[i].w));
            *(uint2*)(feat + (size_t)rr[i] * 32 + 4 * dg) = cv.u;   // 8B aligned
        }
    }
}

// ---------------------------------------------------------------------------
// K2: fully fused per-sample pipeline (verified R5/R6 version, unchanged).
// ---------------------------------------------------------------------------
__global__ __launch_bounds__(1024, 8) void k_fused(
    const __half* __restrict__ feat, const int* __restrict__ skill,
    const int* __restrict__ rnodes, const int* __restrict__ ridx,
    const int* __restrict__ dst_ids,
    const float* __restrict__ w_struct, const float* __restrict__ b_struct,
    const float* __restrict__ ln_g, const float* __restrict__ ln_b,
    const float* __restrict__ Wg, const float* __restrict__ b_gcn,
    const float* __restrict__ Wo, const float* __restrict__ b_out,
    float* __restrict__ out, int B)
{
    __shared__ float Wgl[32 * 32];
    __shared__ float Wol[32 * 32];
    __shared__ float xwT[32][101];
    __shared__ float pooled[32];

    const int t = threadIdx.x, b = blockIdx.x;

    Wgl[t & 1023] = Wg[t & 1023];      // blockDim == 1024: one element each
    Wol[t & 1023] = Wo[t & 1023];

    const int l    = t >> 3;
    const int dg   = t & 7;
    const int lane = t & 63;
    const bool act = (l < 100);

    const int* __restrict__ rb = ridx + b * 5;
    const int cskill = skill[dst_ids[b]];   // same addr across block: broadcast

    int   n0 = 0;
    int   simc = 0;
    float4 acc = f4zero();

    if (act) {
        int nodes[5];
        #pragma unroll
        for (int r = 0; r < 5; ++r) nodes[r] = rnodes[(size_t)rb[r] * 100 + l];
        n0 = nodes[0];
        #pragma unroll
        for (int r = 0; r < 5; ++r) {
            simc += (skill[nodes[r]] == cskill) ? 1 : 0;
            const uint2 raw = *(const uint2*)(feat + (size_t)nodes[r] * 32 + 4 * dg);
            const float2 f01 = __half22float2(*(const __half2*)&raw.x);
            const float2 f23 = __half22float2(*(const __half2*)&raw.y);
            acc.x += f01.x; acc.y += f01.y; acc.z += f23.x; acc.w += f23.y;
        }
    }

    // barrier (covers Wgl/Wol staging) + per-b valid count in one op
    const int valid = __syncthreads_count(act && dg == 0 && n0 > 0);

    float4 o = f4zero();
    if (act) {
        const float simf = (float)simc * 0.2f;
        {
            const float4 ws = ((const float4*)w_struct)[dg];
            const float4 bs = ((const float4*)b_struct)[dg];
            acc.x = fmaf(acc.x, 0.2f, fmaf(simf, ws.x, bs.x));
            acc.y = fmaf(acc.y, 0.2f, fmaf(simf, ws.y, bs.y));
            acc.z = fmaf(acc.z, 0.2f, fmaf(simf, ws.z, bs.z));
            acc.w = fmaf(acc.w, 0.2f, fmaf(simf, ws.w, bs.w));
        }

        // LayerNorm over D=32 = 8 lanes x 4 dims (two-pass, biased var)
        float part = acc.x + acc.y + acc.z + acc.w;
        part += __shfl_xor(part, 1);
        part += __shfl_xor(part, 2);
        part += __shfl_xor(part, 4);
        const float mu = part * (1.f / 32.f);
        float dx, sq;
        dx = acc.x - mu; sq  = dx * dx;
        dx = acc.y - mu; sq  = fmaf(dx, dx, sq);
        dx = acc.z - mu; sq  = fmaf(dx, dx, sq);
        dx = acc.w - mu; sq  = fmaf(dx, dx, sq);
        sq += __shfl_xor(sq, 1);
        sq += __shfl_xor(sq, 2);
        sq += __shfl_xor(sq, 4);
        const float rs = rsqrtf(sq * (1.f / 32.f) + LN_EPS);

        float4 y;
        {
            const float4 g4 = ((const float4*)ln_g)[dg];
            const float4 b4 = ((const float4*)ln_b)[dg];
            y.x = fmaf((acc.x - mu) * rs, g4.x, b4.x);
            y.y = fmaf((acc.y - mu) * rs, g4.y, b4.y);
            y.z = fmaf((acc.z - mu) * rs, g4.z, b4.z);
            y.w = fmaf((acc.w - mu) * rs, g4.w, b4.w);
        }

        // xw quadrant: xw[4dg+j] = sum_k h[k]*Wg[k][4dg+j], h broadcast
        // lazily from the 8-lane group (no h[32] array).
        const float4* __restrict__ W4 = (const float4*)Wgl;
        const int base = lane & ~7;
        #pragma unroll
        for (int s = 0; s < 8; ++s) {
            const float hx = __shfl(y.x, base + s, 64);
            const float hy = __shfl(y.y, base + s, 64);
            const float hz = __shfl(y.z, base + s, 64);
            const float hw = __shfl(y.w, base + s, 64);
            const float4 w0 = W4[(4 * s + 0) * 8 + dg];
            const float4 w1 = W4[(4 * s + 1) * 8 + dg];
            const float4 w2 = W4[(4 * s + 2) * 8 + dg];
            const float4 w3 = W4[(4 * s + 3) * 8 + dg];
            o.x = fmaf(hx, w0.x, o.x);
            o.y = fmaf(hx, w0.y, o.y);
            o.z = fmaf(hx, w0.z, o.z);
            o.w = fmaf(hx, w0.w, o.w);
            o.x = fmaf(hy, w1.x, o.x);
            o.y = fmaf(hy, w1.y, o.y);
            o.z = fmaf(hy, w1.z, o.z);
            o.w = fmaf(hy, w1.w, o.w);
            o.x = fmaf(hz, w2.x, o.x);
            o.y = fmaf(hz, w2.y, o.y);
            o.z = fmaf(hz, w2.z, o.z);
            o.w = fmaf(hz, w2.w, o.w);
            o.x = fmaf(hw, w3.x, o.x);
            o.y = fmaf(hw, w3.y, o.y);
            o.z = fmaf(hw, w3.z, o.z);
            o.w = fmaf(hw, w3.w, o.w);
        }

        // publish xw quadrant to LDS (banks 2-way max: free)
        xwT[4 * dg + 0][l] = o.x;
        xwT[4 * dg + 1][l] = o.y;
        xwT[4 * dg + 2][l] = o.z;
        xwT[4 * dg + 3][l] = o.w;
    }
    __syncthreads();

    // chain-GCN: out[l] = xw[l]/deg[l] + edge(l-1->l)*xw[l-1]*rsqrt(deg[l-1]deg[l]);
    // gnn = relu(out + b_gcn). deg[0]=1; deg[v>=1] = 1 + (v < valid).
    if (act) {
        const bool hm = (l >= 1) && (l < valid);
        const float degl  = 1.f + ((l >= 1 && l < valid) ? 1.f : 0.f);
        const float deglm = 1.f + ((l - 1 >= 1 && (l - 1) < valid) ? 1.f : 0.f);
        const float invd  = 1.f / degl;                    // deg in {1,2}: exact
        const float invn  = hm ? rsqrtf(deglm * degl) : 0.f;
        const int lm = hm ? (l - 1) : l;                   // safe LDS index when !hm
        const float4 bg4 = ((const float4*)b_gcn)[dg];
        float m;
        m = hm ? xwT[4 * dg + 0][lm] * invn : 0.f;
        o.x = fmaxf(fmaf(o.x, invd, m) + bg4.x, 0.f);
        m = hm ? xwT[4 * dg + 1][lm] * invn : 0.f;
        o.y = fmaxf(fmaf(o.y, invd, m) + bg4.y, 0.f);
        m = hm ? xwT[4 * dg + 2][lm] * invn : 0.f;
        o.z = fmaxf(fmaf(o.z, invd, m) + bg4.z, 0.f);
        m = hm ? xwT[4 * dg + 3][lm] * invn : 0.f;
        o.w = fmaxf(fmaf(o.w, invd, m) + bg4.w, 0.f);
    }
    __syncthreads();   // all xwT reads done before overwrite (WAR)

    if (act) {
        xwT[4 * dg + 0][l] = o.x;
        xwT[4 * dg + 1][l] = o.y;
        xwT[4 * dg + 2][l] = o.z;
        xwT[4 * dg + 3][l] = o.w;
    }
    __syncthreads();

    // global_mean_pool over L=100 (32 lanes, reads (5t+j)%32: conflict-free)
    if (t < 32) {
        float s = 0.f;
        for (int j = 0; j < 100; ++j) s += xwT[t][j];
        pooled[t] = s * 0.01f;
    }
    __syncthreads();

    if (t < 32) {
        float s = b_out[t];
        #pragma unroll 8
        for (int k = 0; k < 32; ++k) s = fmaf(pooled[k], Wol[k * 32 + t], s);
        out[(size_t)b * 32 + t] = s;                       // src_emb
    } else if (t < 64) {
        const int d = t - 32;
        const __half* fr = feat + (size_t)dst_ids[b] * 32; // broadcast reads
        float s = b_out[d];
        #pragma unroll 8
        for (int k = 0; k < 32; ++k)
            s = fmaf(__half2float(fr[k]), Wol[k * 32 + d], s);
        out[(size_t)B * 32 + (size_t)b * 32 + d] = s;      // dst_emb
    }
}

// ---------------------------------------------------------------------------
extern "C" void kernel_launch(void* const* d_in, const int* in_sizes, int n_in,
                              void* d_out, int out_size, void* d_ws, size_t ws_size,
                              hipStream_t stream)
{
    const float* X      = (const float*)d_in[0];   // [N,128]
    const int*   rnodes = (const int*)  d_in[1];   // [P,100]
    const int*   ridx   = (const int*)  d_in[2];   // [B,5]
    /* d_in[3] src_node_ids: unused by reference */
    const int*   dst    = (const int*)  d_in[4];   // [B]
    /* d_in[5] node_interact_times: unused */
    const float* Wf  = (const float*)d_in[6];
    const float* bf  = (const float*)d_in[7];
    const float* wst = (const float*)d_in[8];
    const float* bst = (const float*)d_in[9];
    const float* lg  = (const float*)d_in[10];
    const float* lb  = (const float*)d_in[11];
    const float* Wg  = (const float*)d_in[12];
    const float* bg  = (const float*)d_in[13];
    const float* Wo  = (const float*)d_in[14];
    const float* bo  = (const float*)d_in[15];

    const int N = in_sizes[0] / 128;   // 100000
    const int B = in_sizes[4];         // 1024

    // workspace: feat_all [N,32] fp16 (6.4MB) | skill [N] i32 (16B-aligned)
    __half* feat = (__half*)d_ws;
    size_t feat_bytes = (((size_t)N * 32 * sizeof(__half)) + 15) & ~(size_t)15;
    int* skill = (int*)((char*)d_ws + feat_bytes);
    float* out = (float*)d_out;

    const int q = (N + 3) >> 2;
    k_feat<<<(q * 8 + 255) / 256, 256, 0, stream>>>(X, Wf, bf, feat, skill, N);
    k_fused<<<B, 1024, 0, stream>>>(feat, skill, rnodes, ridx, dst,
                                    wst, bst, lg, lb, Wg, bg, Wo, bo, out, B);
}

// Round 10
// 163.308 us; speedup vs baseline: 1.0844x; 1.0844x over previous
//
#include <hip/hip_runtime.h>
#include <hip/hip_fp16.h>

#define LN_EPS 1e-5f

static __device__ __forceinline__ float4 f4zero() { return make_float4(0.f, 0.f, 0.f, 0.f); }

// ---------------------------------------------------------------------------
// K1: feat[N][32](fp16) = X[N][128] @ Wf[128][32] + bf ; skill[N] = (int)X[n][0]
// R-sweep measured: R=1 -> 31us (LDS-issue-bound), R=4 -> 51us (3125 waves,
// TLP-starved, R9). R=2 is the knee: 15.6us LDS issue, 6250 waves (24/CU).
// launch_bounds(256,4) = 128-VGPR budget (R7's (256,8) cap of 64 spilled
// this exact structure to scratch). Explicit 1-deep prefetch keeps 2 X-loads
// in flight per wave so load latency hides under the 32 FMAs per iteration.
// Rows r and r+N/2: both streams wave-coalesced.
// ---------------------------------------------------------------------------
__global__ __launch_bounds__(256, 4) void k_feat(
    const float* __restrict__ X, const float* __restrict__ Wf,
    const float* __restrict__ bf, __half* __restrict__ feat,
    int* __restrict__ skill, int N)
{
    __shared__ float Wl[128 * 32];
    for (int i = threadIdx.x; i < 128 * 32; i += 256) Wl[i] = Wf[i];
    __syncthreads();

    const int gid  = blockIdx.x * 256 + threadIdx.x;
    const int r0   = gid >> 3;         // thread handles rows r0 and r0+half
    const int dg   = gid & 7;          // dims 4*dg .. 4*dg+3
    const int half = (N + 1) >> 1;
    if (r0 >= half) return;
    const int r1 = r0 + half;
    const bool v1 = (r1 < N);          // always true for even N; guard kept

    const float4* __restrict__ X0 = (const float4*)X + (size_t)r0 * 32;
    const float4* __restrict__ X1 = (const float4*)X + (size_t)(v1 ? r1 : r0) * 32;
    const float4* __restrict__ W4 = (const float4*)Wl;

    const float4 bias = *(const float4*)(bf + 4 * dg);
    float4 acc0 = bias, acc1 = bias;

    // prefetch f4 = 0
    float4 xv0 = X0[0];
    float4 xv1 = X1[0];
    if (dg == 0) {
        skill[r0] = (int)xv0.x;                 // trunc == astype(int32)
        if (v1) skill[r1] = (int)xv1.x;
    }

    #pragma unroll 2
    for (int f4 = 0; f4 < 32; ++f4) {
        // issue next iteration's loads BEFORE consuming this one's
        float4 nx0 = f4zero(), nx1 = f4zero();
        if (f4 < 31) { nx0 = X0[f4 + 1]; nx1 = X1[f4 + 1]; }

        const float4 w0 = W4[(4 * f4 + 0) * 8 + dg];
        const float4 w1 = W4[(4 * f4 + 1) * 8 + dg];
        const float4 w2 = W4[(4 * f4 + 2) * 8 + dg];
        const float4 w3 = W4[(4 * f4 + 3) * 8 + dg];

        acc0.x = fmaf(xv0.x, w0.x, acc0.x);
        acc0.y = fmaf(xv0.x, w0.y, acc0.y);
        acc0.z = fmaf(xv0.x, w0.z, acc0.z);
        acc0.w = fmaf(xv0.x, w0.w, acc0.w);
        acc1.x = fmaf(xv1.x, w0.x, acc1.x);
        acc1.y = fmaf(xv1.x, w0.y, acc1.y);
        acc1.z = fmaf(xv1.x, w0.z, acc1.z);
        acc1.w = fmaf(xv1.x, w0.w, acc1.w);
        acc0.x = fmaf(xv0.y, w1.x, acc0.x);
        acc0.y = fmaf(xv0.y, w1.y, acc0.y);
        acc0.z = fmaf(xv0.y, w1.z, acc0.z);
        acc0.w = fmaf(xv0.y, w1.w, acc0.w);
        acc1.x = fmaf(xv1.y, w1.x, acc1.x);
        acc1.y = fmaf(xv1.y, w1.y, acc1.y);
        acc1.z = fmaf(xv1.y, w1.z, acc1.z);
        acc1.w = fmaf(xv1.y, w1.w, acc1.w);
        acc0.x = fmaf(xv0.z, w2.x, acc0.x);
        acc0.y = fmaf(xv0.z, w2.y, acc0.y);
        acc0.z = fmaf(xv0.z, w2.z, acc0.z);
        acc0.w = fmaf(xv0.z, w2.w, acc0.w);
        acc1.x = fmaf(xv1.z, w2.x, acc1.x);
        acc1.y = fmaf(xv1.z, w2.y, acc1.y);
        acc1.z = fmaf(xv1.z, w2.z, acc1.z);
        acc1.w = fmaf(xv1.z, w2.w, acc1.w);
        acc0.x = fmaf(xv0.w, w3.x, acc0.x);
        acc0.y = fmaf(xv0.w, w3.y, acc0.y);
        acc0.z = fmaf(xv0.w, w3.z, acc0.z);
        acc0.w = fmaf(xv0.w, w3.w, acc0.w);
        acc1.x = fmaf(xv1.w, w3.x, acc1.x);
        acc1.y = fmaf(xv1.w, w3.y, acc1.y);
        acc1.z = fmaf(xv1.w, w3.z, acc1.z);
        acc1.w = fmaf(xv1.w, w3.w, acc1.w);

        xv0 = nx0; xv1 = nx1;
    }

    union { __half2 h2[2]; uint2 u; } cv;
    cv.h2[0] = __float22half2_rn(make_float2(acc0.x, acc0.y));
    cv.h2[1] = __float22half2_rn(make_float2(acc0.z, acc0.w));
    *(uint2*)(feat + (size_t)r0 * 32 + 4 * dg) = cv.u;    // 8B aligned
    if (v1) {
        cv.h2[0] = __float22half2_rn(make_float2(acc1.x, acc1.y));
        cv.h2[1] = __float22half2_rn(make_float2(acc1.z, acc1.w));
        *(uint2*)(feat + (size_t)r1 * 32 + 4 * dg) = cv.u;
    }
}

// ---------------------------------------------------------------------------
// K2: fully fused per-sample pipeline (verified R5/R6 version, unchanged).
// ---------------------------------------------------------------------------
__global__ __launch_bounds__(1024, 8) void k_fused(
    const __half* __restrict__ feat, const int* __restrict__ skill,
    const int* __restrict__ rnodes, const int* __restrict__ ridx,
    const int* __restrict__ dst_ids,
    const float* __restrict__ w_struct, const float* __restrict__ b_struct,
    const float* __restrict__ ln_g, const float* __restrict__ ln_b,
    const float* __restrict__ Wg, const float* __restrict__ b_gcn,
    const float* __restrict__ Wo, const float* __restrict__ b_out,
    float* __restrict__ out, int B)
{
    __shared__ float Wgl[32 * 32];
    __shared__ float Wol[32 * 32];
    __shared__ float xwT[32][101];
    __shared__ float pooled[32];

    const int t = threadIdx.x, b = blockIdx.x;

    Wgl[t & 1023] = Wg[t & 1023];      // blockDim == 1024: one element each
    Wol[t & 1023] = Wo[t & 1023];

    const int l    = t >> 3;
    const int dg   = t & 7;
    const int lane = t & 63;
    const bool act = (l < 100);

    const int* __restrict__ rb = ridx + b * 5;
    const int cskill = skill[dst_ids[b]];   // same addr across block: broadcast

    int   n0 = 0;
    int   simc = 0;
    float4 acc = f4zero();

    if (act) {
        int nodes[5];
        #pragma unroll
        for (int r = 0; r < 5; ++r) nodes[r] = rnodes[(size_t)rb[r] * 100 + l];
        n0 = nodes[0];
        #pragma unroll
        for (int r = 0; r < 5; ++r) {
            simc += (skill[nodes[r]] == cskill) ? 1 : 0;
            const uint2 raw = *(const uint2*)(feat + (size_t)nodes[r] * 32 + 4 * dg);
            const float2 f01 = __half22float2(*(const __half2*)&raw.x);
            const float2 f23 = __half22float2(*(const __half2*)&raw.y);
            acc.x += f01.x; acc.y += f01.y; acc.z += f23.x; acc.w += f23.y;
        }
    }

    // barrier (covers Wgl/Wol staging) + per-b valid count in one op
    const int valid = __syncthreads_count(act && dg == 0 && n0 > 0);

    float4 o = f4zero();
    if (act) {
        const float simf = (float)simc * 0.2f;
        {
            const float4 ws = ((const float4*)w_struct)[dg];
            const float4 bs = ((const float4*)b_struct)[dg];
            acc.x = fmaf(acc.x, 0.2f, fmaf(simf, ws.x, bs.x));
            acc.y = fmaf(acc.y, 0.2f, fmaf(simf, ws.y, bs.y));
            acc.z = fmaf(acc.z, 0.2f, fmaf(simf, ws.z, bs.z));
            acc.w = fmaf(acc.w, 0.2f, fmaf(simf, ws.w, bs.w));
        }

        // LayerNorm over D=32 = 8 lanes x 4 dims (two-pass, biased var)
        float part = acc.x + acc.y + acc.z + acc.w;
        part += __shfl_xor(part, 1);
        part += __shfl_xor(part, 2);
        part += __shfl_xor(part, 4);
        const float mu = part * (1.f / 32.f);
        float dx, sq;
        dx = acc.x - mu; sq  = dx * dx;
        dx = acc.y - mu; sq  = fmaf(dx, dx, sq);
        dx = acc.z - mu; sq  = fmaf(dx, dx, sq);
        dx = acc.w - mu; sq  = fmaf(dx, dx, sq);
        sq += __shfl_xor(sq, 1);
        sq += __shfl_xor(sq, 2);
        sq += __shfl_xor(sq, 4);
        const float rs = rsqrtf(sq * (1.f / 32.f) + LN_EPS);

        float4 y;
        {
            const float4 g4 = ((const float4*)ln_g)[dg];
            const float4 b4 = ((const float4*)ln_b)[dg];
            y.x = fmaf((acc.x - mu) * rs, g4.x, b4.x);
            y.y = fmaf((acc.y - mu) * rs, g4.y, b4.y);
            y.z = fmaf((acc.z - mu) * rs, g4.z, b4.z);
            y.w = fmaf((acc.w - mu) * rs, g4.w, b4.w);
        }

        // xw quadrant: xw[4dg+j] = sum_k h[k]*Wg[k][4dg+j], h broadcast
        // lazily from the 8-lane group (no h[32] array).
        const float4* __restrict__ W4 = (const float4*)Wgl;
        const int base = lane & ~7;
        #pragma unroll
        for (int s = 0; s < 8; ++s) {
            const float hx = __shfl(y.x, base + s, 64);
            const float hy = __shfl(y.y, base + s, 64);
            const float hz = __shfl(y.z, base + s, 64);
            const float hw = __shfl(y.w, base + s, 64);
            const float4 w0 = W4[(4 * s + 0) * 8 + dg];
            const float4 w1 = W4[(4 * s + 1) * 8 + dg];
            const float4 w2 = W4[(4 * s + 2) * 8 + dg];
            const float4 w3 = W4[(4 * s + 3) * 8 + dg];
            o.x = fmaf(hx, w0.x, o.x);
            o.y = fmaf(hx, w0.y, o.y);
            o.z = fmaf(hx, w0.z, o.z);
            o.w = fmaf(hx, w0.w, o.w);
            o.x = fmaf(hy, w1.x, o.x);
            o.y = fmaf(hy, w1.y, o.y);
            o.z = fmaf(hy, w1.z, o.z);
            o.w = fmaf(hy, w1.w, o.w);
            o.x = fmaf(hz, w2.x, o.x);
            o.y = fmaf(hz, w2.y, o.y);
            o.z = fmaf(hz, w2.z, o.z);
            o.w = fmaf(hz, w2.w, o.w);
            o.x = fmaf(hw, w3.x, o.x);
            o.y = fmaf(hw, w3.y, o.y);
            o.z = fmaf(hw, w3.z, o.z);
            o.w = fmaf(hw, w3.w, o.w);
        }

        // publish xw quadrant to LDS (banks 2-way max: free)
        xwT[4 * dg + 0][l] = o.x;
        xwT[4 * dg + 1][l] = o.y;
        xwT[4 * dg + 2][l] = o.z;
        xwT[4 * dg + 3][l] = o.w;
    }
    __syncthreads();

    // chain-GCN: out[l] = xw[l]/deg[l] + edge(l-1->l)*xw[l-1]*rsqrt(deg[l-1]deg[l]);
    // gnn = relu(out + b_gcn). deg[0]=1; deg[v>=1] = 1 + (v < valid).
    if (act) {
        const bool hm = (l >= 1) && (l < valid);
        const float degl  = 1.f + ((l >= 1 && l < valid) ? 1.f : 0.f);
        const float deglm = 1.f + ((l - 1 >= 1 && (l - 1) < valid) ? 1.f : 0.f);
        const float invd  = 1.f / degl;                    // deg in {1,2}: exact
        const float invn  = hm ? rsqrtf(deglm * degl) : 0.f;
        const int lm = hm ? (l - 1) : l;                   // safe LDS index when !hm
        const float4 bg4 = ((const float4*)b_gcn)[dg];
        float m;
        m = hm ? xwT[4 * dg + 0][lm] * invn : 0.f;
        o.x = fmaxf(fmaf(o.x, invd, m) + bg4.x, 0.f);
        m = hm ? xwT[4 * dg + 1][lm] * invn : 0.f;
        o.y = fmaxf(fmaf(o.y, invd, m) + bg4.y, 0.f);
        m = hm ? xwT[4 * dg + 2][lm] * invn : 0.f;
        o.z = fmaxf(fmaf(o.z, invd, m) + bg4.z, 0.f);
        m = hm ? xwT[4 * dg + 3][lm] * invn : 0.f;
        o.w = fmaxf(fmaf(o.w, invd, m) + bg4.w, 0.f);
    }
    __syncthreads();   // all xwT reads done before overwrite (WAR)

    if (act) {
        xwT[4 * dg + 0][l] = o.x;
        xwT[4 * dg + 1][l] = o.y;
        xwT[4 * dg + 2][l] = o.z;
        xwT[4 * dg + 3][l] = o.w;
    }
    __syncthreads();

    // global_mean_pool over L=100 (32 lanes, reads (5t+j)%32: conflict-free)
    if (t < 32) {
        float s = 0.f;
        for (int j = 0; j < 100; ++j) s += xwT[t][j];
        pooled[t] = s * 0.01f;
    }
    __syncthreads();

    if (t < 32) {
        float s = b_out[t];
        #pragma unroll 8
        for (int k = 0; k < 32; ++k) s = fmaf(pooled[k], Wol[k * 32 + t], s);
        out[(size_t)b * 32 + t] = s;                       // src_emb
    } else if (t < 64) {
        const int d = t - 32;
        const __half* fr = feat + (size_t)dst_ids[b] * 32; // broadcast reads
        float s = b_out[d];
        #pragma unroll 8
        for (int k = 0; k < 32; ++k)
            s = fmaf(__half2float(fr[k]), Wol[k * 32 + d], s);
        out[(size_t)B * 32 + (size_t)b * 32 + d] = s;      // dst_emb
    }
}

// ---------------------------------------------------------------------------
extern "C" void kernel_launch(void* const* d_in, const int* in_sizes, int n_in,
                              void* d_out, int out_size, void* d_ws, size_t ws_size,
                              hipStream_t stream)
{
    const float* X      = (const float*)d_in[0];   // [N,128]
    const int*   rnodes = (const int*)  d_in[1];   // [P,100]
    const int*   ridx   = (const int*)  d_in[2];   // [B,5]
    /* d_in[3] src_node_ids: unused by reference */
    const int*   dst    = (const int*)  d_in[4];   // [B]
    /* d_in[5] node_interact_times: unused */
    const float* Wf  = (const float*)d_in[6];
    const float* bf  = (const float*)d_in[7];
    const float* wst = (const float*)d_in[8];
    const float* bst = (const float*)d_in[9];
    const float* lg  = (const float*)d_in[10];
    const float* lb  = (const float*)d_in[11];
    const float* Wg  = (const float*)d_in[12];
    const float* bg  = (const float*)d_in[13];
    const float* Wo  = (const float*)d_in[14];
    const float* bo  = (const float*)d_in[15];

    const int N = in_sizes[0] / 128;   // 100000
    const int B = in_sizes[4];         // 1024

    // workspace: feat_all [N,32] fp16 (6.4MB) | skill [N] i32 (16B-aligned)
    __half* feat = (__half*)d_ws;
    size_t feat_bytes = (((size_t)N * 32 * sizeof(__half)) + 15) & ~(size_t)15;
    int* skill = (int*)((char*)d_ws + feat_bytes);
    float* out = (float*)d_out;

    const int half = (N + 1) >> 1;
    k_feat<<<(half * 8 + 255) / 256, 256, 0, stream>>>(X, Wf, bf, feat, skill, N);
    k_fused<<<B, 1024, 0, stream>>>(feat, skill, rnodes, ridx, dst,
                                    wst, bst, lg, lb, Wg, bg, Wo, bo, out, B);
}

// Round 11
// 153.405 us; speedup vs baseline: 1.1544x; 1.0646x over previous
//
#include <hip/hip_runtime.h>
#include <hip/hip_fp16.h>

#define LN_EPS 1e-5f

static __device__ __forceinline__ float4 f4zero() { return make_float4(0.f, 0.f, 0.f, 0.f); }

// ---------------------------------------------------------------------------
// K1: feat[N][32](fp16) = X[N][128] @ Wf[128][32] + bf ; skill[N] = (int)X[n][0]
// (verified R10 version, unchanged: R=2 rows/thread + 1-deep prefetch,
// launch_bounds(256,4) so the ~70-reg live set fits without spill.)
// ---------------------------------------------------------------------------
__global__ __launch_bounds__(256, 4) void k_feat(
    const float* __restrict__ X, const float* __restrict__ Wf,
    const float* __restrict__ bf, __half* __restrict__ feat,
    int* __restrict__ skill, int N)
{
    __shared__ float Wl[128 * 32];
    for (int i = threadIdx.x; i < 128 * 32; i += 256) Wl[i] = Wf[i];
    __syncthreads();

    const int gid  = blockIdx.x * 256 + threadIdx.x;
    const int r0   = gid >> 3;         // thread handles rows r0 and r0+half
    const int dg   = gid & 7;          // dims 4*dg .. 4*dg+3
    const int half = (N + 1) >> 1;
    if (r0 >= half) return;
    const int r1 = r0 + half;
    const bool v1 = (r1 < N);

    const float4* __restrict__ X0 = (const float4*)X + (size_t)r0 * 32;
    const float4* __restrict__ X1 = (const float4*)X + (size_t)(v1 ? r1 : r0) * 32;
    const float4* __restrict__ W4 = (const float4*)Wl;

    const float4 bias = *(const float4*)(bf + 4 * dg);
    float4 acc0 = bias, acc1 = bias;

    float4 xv0 = X0[0];
    float4 xv1 = X1[0];
    if (dg == 0) {
        skill[r0] = (int)xv0.x;                 // trunc == astype(int32)
        if (v1) skill[r1] = (int)xv1.x;
    }

    #pragma unroll 2
    for (int f4 = 0; f4 < 32; ++f4) {
        float4 nx0 = f4zero(), nx1 = f4zero();
        if (f4 < 31) { nx0 = X0[f4 + 1]; nx1 = X1[f4 + 1]; }

        const float4 w0 = W4[(4 * f4 + 0) * 8 + dg];
        const float4 w1 = W4[(4 * f4 + 1) * 8 + dg];
        const float4 w2 = W4[(4 * f4 + 2) * 8 + dg];
        const float4 w3 = W4[(4 * f4 + 3) * 8 + dg];

        acc0.x = fmaf(xv0.x, w0.x, acc0.x);
        acc0.y = fmaf(xv0.x, w0.y, acc0.y);
        acc0.z = fmaf(xv0.x, w0.z, acc0.z);
        acc0.w = fmaf(xv0.x, w0.w, acc0.w);
        acc1.x = fmaf(xv1.x, w0.x, acc1.x);
        acc1.y = fmaf(xv1.x, w0.y, acc1.y);
        acc1.z = fmaf(xv1.x, w0.z, acc1.z);
        acc1.w = fmaf(xv1.x, w0.w, acc1.w);
        acc0.x = fmaf(xv0.y, w1.x, acc0.x);
        acc0.y = fmaf(xv0.y, w1.y, acc0.y);
        acc0.z = fmaf(xv0.y, w1.z, acc0.z);
        acc0.w = fmaf(xv0.y, w1.w, acc0.w);
        acc1.x = fmaf(xv1.y, w1.x, acc1.x);
        acc1.y = fmaf(xv1.y, w1.y, acc1.y);
        acc1.z = fmaf(xv1.y, w1.z, acc1.z);
        acc1.w = fmaf(xv1.y, w1.w, acc1.w);
        acc0.x = fmaf(xv0.z, w2.x, acc0.x);
        acc0.y = fmaf(xv0.z, w2.y, acc0.y);
        acc0.z = fmaf(xv0.z, w2.z, acc0.z);
        acc0.w = fmaf(xv0.z, w2.w, acc0.w);
        acc1.x = fmaf(xv1.z, w2.x, acc1.x);
        acc1.y = fmaf(xv1.z, w2.y, acc1.y);
        acc1.z = fmaf(xv1.z, w2.z, acc1.z);
        acc1.w = fmaf(xv1.z, w2.w, acc1.w);
        acc0.x = fmaf(xv0.w, w3.x, acc0.x);
        acc0.y = fmaf(xv0.w, w3.y, acc0.y);
        acc0.z = fmaf(xv0.w, w3.z, acc0.z);
        acc0.w = fmaf(xv0.w, w3.w, acc0.w);
        acc1.x = fmaf(xv1.w, w3.x, acc1.x);
        acc1.y = fmaf(xv1.w, w3.y, acc1.y);
        acc1.z = fmaf(xv1.w, w3.z, acc1.z);
        acc1.w = fmaf(xv1.w, w3.w, acc1.w);

        xv0 = nx0; xv1 = nx1;
    }

    union { __half2 h2[2]; uint2 u; } cv;
    cv.h2[0] = __float22half2_rn(make_float2(acc0.x, acc0.y));
    cv.h2[1] = __float22half2_rn(make_float2(acc0.z, acc0.w));
    *(uint2*)(feat + (size_t)r0 * 32 + 4 * dg) = cv.u;
    if (v1) {
        cv.h2[0] = __float22half2_rn(make_float2(acc1.x, acc1.y));
        cv.h2[1] = __float22half2_rn(make_float2(acc1.z, acc1.w));
        *(uint2*)(feat + (size_t)r1 * 32 + 4 * dg) = cv.u;
    }
}

// ---------------------------------------------------------------------------
// K2: fused per-sample pipeline, restructured to 4 threads/row (dg2 = 8-dim
// group, 16B uint4 feat gathers) + skill-sim on sub-lane 0 only (shfl
// broadcast): 45 memory requests/row vs 120 in the 8-thread version --
// the gather phase is request-rate-bound. 512 threads/block,
// launch_bounds(512,6): VGPR cap 85 (live ~55, no spill), 3 blocks/CU.
// LN reduce: 8 dims in-thread + 2 shfl_xor. GEMV: k ascending (same FP
// order). xwT writes/reads 2-way banks (free); pool 5t+j coprime-32.
// ---------------------------------------------------------------------------
__global__ __launch_bounds__(512, 6) void k_fused(
    const __half* __restrict__ feat, const int* __restrict__ skill,
    const int* __restrict__ rnodes, const int* __restrict__ ridx,
    const int* __restrict__ dst_ids,
    const float* __restrict__ w_struct, const float* __restrict__ b_struct,
    const float* __restrict__ ln_g, const float* __restrict__ ln_b,
    const float* __restrict__ Wg, const float* __restrict__ b_gcn,
    const float* __restrict__ Wo, const float* __restrict__ b_out,
    float* __restrict__ out, int B)
{
    __shared__ float Wgl[32 * 32];
    __shared__ float Wol[32 * 32];
    __shared__ float xwT[32][101];
    __shared__ float pooled[32];

    const int t = threadIdx.x, b = blockIdx.x;

    for (int i = t; i < 1024; i += 512) { Wgl[i] = Wg[i]; Wol[i] = Wo[i]; }

    const int l    = t >> 2;           // row 0..127 (active < 100)
    const int dg2  = t & 3;            // dims 8*dg2 .. 8*dg2+7
    const int lane = t & 63;
    const bool act = (l < 100);
    const int qa = 2 * dg2, qb = 2 * dg2 + 1;

    const int* __restrict__ rb = ridx + b * 5;
    const int cskill = skill[dst_ids[b]];

    int n0 = 0, simc = 0;
    float4 a0 = f4zero(), a1 = f4zero();

    if (act) {
        int nodes[5];
        #pragma unroll
        for (int r = 0; r < 5; ++r) nodes[r] = rnodes[(size_t)rb[r] * 100 + l];
        n0 = nodes[0];
        if (dg2 == 0) {
            #pragma unroll
            for (int r = 0; r < 5; ++r)
                simc += (skill[nodes[r]] == cskill) ? 1 : 0;
        }
        #pragma unroll
        for (int r = 0; r < 5; ++r) {
            const uint4 raw = *(const uint4*)(feat + (size_t)nodes[r] * 32 + 8 * dg2);
            const float2 f0 = __half22float2(*(const __half2*)&raw.x);
            const float2 f1 = __half22float2(*(const __half2*)&raw.y);
            const float2 f2 = __half22float2(*(const __half2*)&raw.z);
            const float2 f3 = __half22float2(*(const __half2*)&raw.w);
            a0.x += f0.x; a0.y += f0.y; a0.z += f1.x; a0.w += f1.y;
            a1.x += f2.x; a1.y += f2.y; a1.z += f3.x; a1.w += f3.y;
        }
    }

    // barrier (covers Wgl/Wol staging) + per-b valid count in one op
    const int valid = __syncthreads_count(act && dg2 == 0 && n0 > 0);

    float4 o0 = f4zero(), o1 = f4zero();
    if (act) {
        simc = __shfl(simc, lane & ~3, 64);    // broadcast from sub-lane 0
        const float simf = (float)simc * 0.2f;
        {
            const float4 wsA = ((const float4*)w_struct)[qa];
            const float4 wsB = ((const float4*)w_struct)[qb];
            const float4 bsA = ((const float4*)b_struct)[qa];
            const float4 bsB = ((const float4*)b_struct)[qb];
            a0.x = fmaf(a0.x, 0.2f, fmaf(simf, wsA.x, bsA.x));
            a0.y = fmaf(a0.y, 0.2f, fmaf(simf, wsA.y, bsA.y));
            a0.z = fmaf(a0.z, 0.2f, fmaf(simf, wsA.z, bsA.z));
            a0.w = fmaf(a0.w, 0.2f, fmaf(simf, wsA.w, bsA.w));
            a1.x = fmaf(a1.x, 0.2f, fmaf(simf, wsB.x, bsB.x));
            a1.y = fmaf(a1.y, 0.2f, fmaf(simf, wsB.y, bsB.y));
            a1.z = fmaf(a1.z, 0.2f, fmaf(simf, wsB.z, bsB.z));
            a1.w = fmaf(a1.w, 0.2f, fmaf(simf, wsB.w, bsB.w));
        }

        // LayerNorm over D=32 = 4 lanes x 8 dims (two-pass, biased var)
        float part = a0.x + a0.y + a0.z + a0.w + a1.x + a1.y + a1.z + a1.w;
        part += __shfl_xor(part, 1);
        part += __shfl_xor(part, 2);
        const float mu = part * (1.f / 32.f);
        float dx, sq;
        dx = a0.x - mu; sq  = dx * dx;
        dx = a0.y - mu; sq  = fmaf(dx, dx, sq);
        dx = a0.z - mu; sq  = fmaf(dx, dx, sq);
        dx = a0.w - mu; sq  = fmaf(dx, dx, sq);
        dx = a1.x - mu; sq  = fmaf(dx, dx, sq);
        dx = a1.y - mu; sq  = fmaf(dx, dx, sq);
        dx = a1.z - mu; sq  = fmaf(dx, dx, sq);
        dx = a1.w - mu; sq  = fmaf(dx, dx, sq);
        sq += __shfl_xor(sq, 1);
        sq += __shfl_xor(sq, 2);
        const float rs = rsqrtf(sq * (1.f / 32.f) + LN_EPS);

        float4 y0, y1;
        {
            const float4 gA = ((const float4*)ln_g)[qa];
            const float4 gB = ((const float4*)ln_g)[qb];
            const float4 bA = ((const float4*)ln_b)[qa];
            const float4 bB = ((const float4*)ln_b)[qb];
            y0.x = fmaf((a0.x - mu) * rs, gA.x, bA.x);
            y0.y = fmaf((a0.y - mu) * rs, gA.y, bA.y);
            y0.z = fmaf((a0.z - mu) * rs, gA.z, bA.z);
            y0.w = fmaf((a0.w - mu) * rs, gA.w, bA.w);
            y1.x = fmaf((a1.x - mu) * rs, gB.x, bB.x);
            y1.y = fmaf((a1.y - mu) * rs, gB.y, bB.y);
            y1.z = fmaf((a1.z - mu) * rs, gB.z, bB.z);
            y1.w = fmaf((a1.w - mu) * rs, gB.w, bB.w);
        }

        // xw[c] = sum_k h[k]*Wg[k][c] for c in 8*dg2..8*dg2+7; h broadcast
        // lazily from the 4-lane group, k ascending (same FP order as ref).
        const float4* __restrict__ W4 = (const float4*)Wgl;
        const int base = lane & ~3;
        #pragma unroll
        for (int s = 0; s < 4; ++s) {
            const float h0 = __shfl(y0.x, base + s, 64);
            const float h1 = __shfl(y0.y, base + s, 64);
            const float h2 = __shfl(y0.z, base + s, 64);
            const float h3 = __shfl(y0.w, base + s, 64);
            const float h4 = __shfl(y1.x, base + s, 64);
            const float h5 = __shfl(y1.y, base + s, 64);
            const float h6 = __shfl(y1.z, base + s, 64);
            const float h7 = __shfl(y1.w, base + s, 64);
            #define GX(J, H) { \
                const float4 wA = W4[(8 * s + (J)) * 8 + qa]; \
                const float4 wB = W4[(8 * s + (J)) * 8 + qb]; \
                o0.x = fmaf(H, wA.x, o0.x); \
                o0.y = fmaf(H, wA.y, o0.y); \
                o0.z = fmaf(H, wA.z, o0.z); \
                o0.w = fmaf(H, wA.w, o0.w); \
                o1.x = fmaf(H, wB.x, o1.x); \
                o1.y = fmaf(H, wB.y, o1.y); \
                o1.z = fmaf(H, wB.z, o1.z); \
                o1.w = fmaf(H, wB.w, o1.w); }
            GX(0, h0) GX(1, h1) GX(2, h2) GX(3, h3)
            GX(4, h4) GX(5, h5) GX(6, h6) GX(7, h7)
            #undef GX
        }

        xwT[8 * dg2 + 0][l] = o0.x;
        xwT[8 * dg2 + 1][l] = o0.y;
        xwT[8 * dg2 + 2][l] = o0.z;
        xwT[8 * dg2 + 3][l] = o0.w;
        xwT[8 * dg2 + 4][l] = o1.x;
        xwT[8 * dg2 + 5][l] = o1.y;
        xwT[8 * dg2 + 6][l] = o1.z;
        xwT[8 * dg2 + 7][l] = o1.w;
    }
    __syncthreads();

    // chain-GCN: out[l] = xw[l]/deg[l] + edge(l-1->l)*xw[l-1]*rsqrt(deg[l-1]deg[l]);
    // gnn = relu(out + b_gcn). deg[0]=1; deg[v>=1] = 1 + (v < valid).
    if (act) {
        const bool hm = (l >= 1) && (l < valid);
        const float degl  = 1.f + ((l >= 1 && l < valid) ? 1.f : 0.f);
        const float deglm = 1.f + ((l - 1 >= 1 && (l - 1) < valid) ? 1.f : 0.f);
        const float invd  = 1.f / degl;
        const float invn  = hm ? rsqrtf(deglm * degl) : 0.f;
        const int lm = hm ? (l - 1) : l;
        const float4 bgA = ((const float4*)b_gcn)[qa];
        const float4 bgB = ((const float4*)b_gcn)[qb];
        float m;
        m = hm ? xwT[8 * dg2 + 0][lm] * invn : 0.f;
        o0.x = fmaxf(fmaf(o0.x, invd, m) + bgA.x, 0.f);
        m = hm ? xwT[8 * dg2 + 1][lm] * invn : 0.f;
        o0.y = fmaxf(fmaf(o0.y, invd, m) + bgA.y, 0.f);
        m = hm ? xwT[8 * dg2 + 2][lm] * invn : 0.f;
        o0.z = fmaxf(fmaf(o0.z, invd, m) + bgA.z, 0.f);
        m = hm ? xwT[8 * dg2 + 3][lm] * invn : 0.f;
        o0.w = fmaxf(fmaf(o0.w, invd, m) + bgA.w, 0.f);
        m = hm ? xwT[8 * dg2 + 4][lm] * invn : 0.f;
        o1.x = fmaxf(fmaf(o1.x, invd, m) + bgB.x, 0.f);
        m = hm ? xwT[8 * dg2 + 5][lm] * invn : 0.f;
        o1.y = fmaxf(fmaf(o1.y, invd, m) + bgB.y, 0.f);
        m = hm ? xwT[8 * dg2 + 6][lm] * invn : 0.f;
        o1.z = fmaxf(fmaf(o1.z, invd, m) + bgB.z, 0.f);
        m = hm ? xwT[8 * dg2 + 7][lm] * invn : 0.f;
        o1.w = fmaxf(fmaf(o1.w, invd, m) + bgB.w, 0.f);
    }
    __syncthreads();   // all xwT reads done before overwrite (WAR)

    if (act) {
        xwT[8 * dg2 + 0][l] = o0.x;
        xwT[8 * dg2 + 1][l] = o0.y;
        xwT[8 * dg2 + 2][l] = o0.z;
        xwT[8 * dg2 + 3][l] = o0.w;
        xwT[8 * dg2 + 4][l] = o1.x;
        xwT[8 * dg2 + 5][l] = o1.y;
        xwT[8 * dg2 + 6][l] = o1.z;
        xwT[8 * dg2 + 7][l] = o1.w;
    }
    __syncthreads();

    // global_mean_pool over L=100 (32 lanes, reads (5t+j)%32: conflict-free)
    if (t < 32) {
        float s = 0.f;
        for (int j = 0; j < 100; ++j) s += xwT[t][j];
        pooled[t] = s * 0.01f;
    }
    __syncthreads();

    if (t < 32) {
        float s = b_out[t];
        #pragma unroll 8
        for (int k = 0; k < 32; ++k) s = fmaf(pooled[k], Wol[k * 32 + t], s);
        out[(size_t)b * 32 + t] = s;                       // src_emb
    } else if (t < 64) {
        const int d = t - 32;
        const __half* fr = feat + (size_t)dst_ids[b] * 32; // broadcast reads
        float s = b_out[d];
        #pragma unroll 8
        for (int k = 0; k < 32; ++k)
            s = fmaf(__half2float(fr[k]), Wol[k * 32 + d], s);
        out[(size_t)B * 32 + (size_t)b * 32 + d] = s;      // dst_emb
    }
}

// ---------------------------------------------------------------------------
extern "C" void kernel_launch(void* const* d_in, const int* in_sizes, int n_in,
                              void* d_out, int out_size, void* d_ws, size_t ws_size,
                              hipStream_t stream)
{
    const float* X      = (const float*)d_in[0];   // [N,128]
    const int*   rnodes = (const int*)  d_in[1];   // [P,100]
    const int*   ridx   = (const int*)  d_in[2];   // [B,5]
    /* d_in[3] src_node_ids: unused by reference */
    const int*   dst    = (const int*)  d_in[4];   // [B]
    /* d_in[5] node_interact_times: unused */
    const float* Wf  = (const float*)d_in[6];
    const float* bf  = (const float*)d_in[7];
    const float* wst = (const float*)d_in[8];
    const float* bst = (const float*)d_in[9];
    const float* lg  = (const float*)d_in[10];
    const float* lb  = (const float*)d_in[11];
    const float* Wg  = (const float*)d_in[12];
    const float* bg  = (const float*)d_in[13];
    const float* Wo  = (const float*)d_in[14];
    const float* bo  = (const float*)d_in[15];

    const int N = in_sizes[0] / 128;   // 100000
    const int B = in_sizes[4];         // 1024

    // workspace: feat_all [N,32] fp16 (6.4MB) | skill [N] i32 (16B-aligned)
    __half* feat = (__half*)d_ws;
    size_t feat_bytes = (((size_t)N * 32 * sizeof(__half)) + 15) & ~(size_t)15;
    int* skill = (int*)((char*)d_ws + feat_bytes);
    float* out = (float*)d_out;

    const int half = (N + 1) >> 1;
    k_feat<<<(half * 8 + 255) / 256, 256, 0, stream>>>(X, Wf, bf, feat, skill, N);
    k_fused<<<B, 512, 0, stream>>>(feat, skill, rnodes, ridx, dst,
                                   wst, bst, lg, lb, Wg, bg, Wo, bo, out, B);
}